// Round 5
// baseline (678.742 us; speedup 1.0000x reference)
//
#include <hip/hip_runtime.h>

#define KOFF 27
#define MPAIR 100000
#define NPAIR (KOFF * MPAIR)        // 2,700,000
#define NOUT 400000
#define CIN 32
#define COUT 32

#define ROWS_PER_BIN 256
#define NBIN ((NOUT + ROWS_PER_BIN - 1) / ROWS_PER_BIN)   // 1563
#define CAPB 3072                   // per-bin slot capacity (avg 1727, +32 sigma)
#define BPB 8192                    // pairs per phase-1 block
#define SPILL_CAP 65536

// ---------- workspace layout (bytes) ----------
// gbin      @ 0      : NBIN*4 = 6252  (padded to 8192)
// spill_cnt @ 8192   : 256
// spill     @ 8448   : SPILL_CAP*8 = 524,288
// binned    @ 532736 : NBIN*CAPB*4 = 19,206,144
// total 19,738,880  (harness ws proven >= 225 MB)
#define O_SPCNT   ((size_t)8192)
#define O_SPILL   ((size_t)8448)
#define O_BINNED  ((size_t)532736)
#define WS_NEED   ((size_t)19738880)

// ---------- Phase 1: block-staged multisplit by output-row bin ----------
__global__ __launch_bounds__(256) void bin_kernel(
    const int* __restrict__ in_map, const int* __restrict__ out_map,
    int* __restrict__ gbin, int* __restrict__ binned,
    int* __restrict__ spill_cnt, int2* __restrict__ spill)
{
    __shared__ int lhist[NBIN];              // count, then running cursor
    const int t = threadIdx.x;
    const int base = blockIdx.x * BPB;

    for (int c = t; c < NBIN; c += 256) lhist[c] = 0;
    __syncthreads();

    // pass A: LDS histogram
    for (int i = t; i < BPB; i += 256) {
        int p = base + i;
        if (p < NPAIR) atomicAdd(&lhist[out_map[p] >> 8], 1);
    }
    __syncthreads();

    // reserve per-(block,bin) chunks in the global bins (hot 6 KB array)
    for (int c = t; c < NBIN; c += 256) {
        int cnt = lhist[c];
        lhist[c] = (cnt > 0) ? atomicAdd(&gbin[c], cnt) : 0;  // -> cursor base
    }
    __syncthreads();

    // pass B: scatter packed (rowlocal<<23 | k<<18 | in_row)
    for (int i = t; i < BPB; i += 256) {
        int p = base + i;
        if (p >= NPAIR) continue;
        int row  = out_map[p];
        int irow = in_map[p];
        int k    = p / MPAIR;                 // constant div -> magic mul
        int bin  = row >> 8;
        int val  = ((row & 255) << 23) | (k << 18) | irow;
        int pos  = atomicAdd(&lhist[bin], 1); // absolute within-bin slot
        if (pos < CAPB) {
            binned[(size_t)bin * CAPB + pos] = val;
        } else {
            int o = atomicAdd(spill_cnt, 1);
            if (o < SPILL_CAP) spill[o] = make_int2(row | (k << 19), irow);
        }
    }
}

// ---------- Phase 2: per-bin k-sorted fused matvec + LDS accumulation ----------
__global__ __launch_bounds__(256) void compute_kernel(
    const float* __restrict__ feats, const float* __restrict__ weight,
    const int* __restrict__ gbin, const int* __restrict__ binned,
    float* __restrict__ out)
{
    __shared__ float tile[ROWS_PER_BIN * COUT];   // 32 KB f32 accumulator
    __shared__ int sorted[CAPB];                  // 12 KB k-sorted pair list
    __shared__ int nk[KOFF], seg[KOFF + 1], choff[KOFF + 1], cur[KOFF];

    const int bin = blockIdx.x;
    const int t = threadIdx.x;
    const int n = min(gbin[bin], CAPB);
    const int* mybin = binned + (size_t)bin * CAPB;

    for (int i = t; i < ROWS_PER_BIN * COUT; i += 256) tile[i] = 0.f;
    if (t < KOFF) nk[t] = 0;
    __syncthreads();

    // count per-k
    for (int i = t; i < n; i += 256)
        atomicAdd(&nk[(mybin[i] >> 18) & 31], 1);
    __syncthreads();

    // serial scan over 27 entries: segment starts + padded chunk offsets
    if (t == 0) {
        int s = 0, c = 0;
        for (int k = 0; k < KOFF; ++k) {
            seg[k] = s; choff[k] = c; cur[k] = s;
            s += nk[k];
            c += (nk[k] + 63) >> 6;
        }
        seg[KOFF] = s; choff[KOFF] = c;
    }
    __syncthreads();

    // scatter into k-sorted order
    for (int i = t; i < n; i += 256) {
        int v = mybin[i];
        int pos = atomicAdd(&cur[(v >> 18) & 31], 1);
        sorted[pos] = v;
    }
    __syncthreads();

    // process k-uniform 64-wide chunks (weights -> scalar loads)
    const int nchunks = choff[KOFF];
    const int wave = t >> 6;
    const int lane = t & 63;

    for (int c = wave; c < nchunks; c += 4) {
        int k = 0;
        while (k < KOFF - 1 && choff[k + 1] <= c) ++k;   // wave-uniform
        int i = ((c - choff[k]) << 6) + lane;
        bool act = i < nk[k];
        int v = act ? sorted[seg[k] + i] : 0;
        int irow = v & 0x3FFFF;
        int rl   = (v >> 23) & 255;

        int ku = __builtin_amdgcn_readfirstlane(k);
        const float* wk = weight + (size_t)ku * (CIN * COUT);

        const float4* frow = reinterpret_cast<const float4*>(feats + (size_t)irow * CIN);
        float4 f4[8];
#pragma unroll
        for (int j = 0; j < 8; ++j) f4[j] = frow[j];
        const float* f = reinterpret_cast<const float*>(f4);

        float acc[COUT];
#pragma unroll
        for (int j = 0; j < COUT; ++j) acc[j] = 0.f;
#pragma unroll
        for (int ci = 0; ci < CIN; ++ci) {
            float fv = f[ci];
#pragma unroll
            for (int co = 0; co < COUT; ++co)
                acc[co] = fmaf(fv, wk[ci * COUT + co], acc[co]);
        }

        if (act) {
#pragma unroll
            for (int j = 0; j < COUT; ++j) {
                int co = (lane + j) & 31;                 // stagger: bank = co
                atomicAdd(&tile[rl * COUT + co], acc[co]);
            }
        }
    }
    __syncthreads();

    // coalesced tile -> out (each row covered by exactly one bin)
    const size_t obase = (size_t)(bin << 8) * COUT;
    for (int i = t; i < ROWS_PER_BIN * COUT; i += 256) {
        int grow = (bin << 8) + (i >> 5);
        if (grow < NOUT) out[obase + i] = tile[i];
    }
}

// ---------- Phase 3: statistically-rare bin overflow, recompute + atomics ----------
__global__ __launch_bounds__(256) void spill_kernel(
    const float* __restrict__ feats, const float* __restrict__ weight,
    const int* __restrict__ spill_cnt, const int2* __restrict__ spill,
    float* __restrict__ out)
{
    int n = min(*spill_cnt, SPILL_CAP);
    for (int i = blockIdx.x * blockDim.x + threadIdx.x; i < n * 32;
         i += gridDim.x * blockDim.x) {
        int idx = i >> 5, co = i & 31;
        int2 s = spill[idx];
        int row  = s.x & 0x7FFFF;
        int k    = (s.x >> 19) & 31;
        int irow = s.y;
        const float* f  = feats + (size_t)irow * CIN;
        const float* wk = weight + (size_t)k * (CIN * COUT);
        float acc = 0.f;
#pragma unroll
        for (int ci = 0; ci < CIN; ++ci)
            acc = fmaf(f[ci], wk[ci * COUT + co], acc);
        atomicAdd(&out[(size_t)row * COUT + co], acc);
    }
}

// ---------- last-resort fallback (tiny ws): R1 atomic scatter ----------
__global__ __launch_bounds__(256) void spconvt_fallback(
    const float* __restrict__ feats, const float* __restrict__ weight,
    const int* __restrict__ in_map, const int* __restrict__ out_map,
    float* __restrict__ out)
{
    const int k = blockIdx.y;
    const int m = blockIdx.x * blockDim.x + threadIdx.x;
    const bool active = (m < MPAIR);
    const int mm = active ? m : (MPAIR - 1);
    const int pair = k * MPAIR + mm;
    const int in_row = in_map[pair];
    const int out_row = out_map[pair];
    const float4* frow = reinterpret_cast<const float4*>(feats + (size_t)in_row * CIN);
    float4 f4[8];
#pragma unroll
    for (int i = 0; i < 8; ++i) f4[i] = frow[i];
    const float* f = reinterpret_cast<const float*>(f4);
    float acc[COUT];
#pragma unroll
    for (int i = 0; i < COUT; ++i) acc[i] = 0.f;
    const float* wk = weight + (size_t)k * (CIN * COUT);
#pragma unroll
    for (int ci = 0; ci < CIN; ++ci) {
        const float fv = f[ci];
#pragma unroll
        for (int co = 0; co < COUT; ++co)
            acc[co] = fmaf(fv, wk[ci * COUT + co], acc[co]);
    }
    if (active) {
        float* orow = out + (size_t)out_row * COUT;
#pragma unroll
        for (int co = 0; co < COUT; ++co) atomicAdd(orow + co, acc[co]);
    }
}

extern "C" void kernel_launch(void* const* d_in, const int* in_sizes, int n_in,
                              void* d_out, int out_size, void* d_ws, size_t ws_size,
                              hipStream_t stream) {
    const float* feats  = (const float*)d_in[0];
    const float* weight = (const float*)d_in[1];
    const int* in_map   = (const int*)d_in[2];
    const int* out_map  = (const int*)d_in[3];
    float* out          = (float*)d_out;
    char* ws            = (char*)d_ws;

    if (ws_size >= WS_NEED) {
        int* gbin      = (int*)(ws);
        int* spill_cnt = (int*)(ws + O_SPCNT);
        int2* spill    = (int2*)(ws + O_SPILL);
        int* binned    = (int*)(ws + O_BINNED);

        // zero only the counters (8.5 KB)
        hipMemsetAsync(ws, 0, O_SPILL, stream);

        bin_kernel<<<dim3((NPAIR + BPB - 1) / BPB), dim3(256), 0, stream>>>(
            in_map, out_map, gbin, binned, spill_cnt, spill);

        compute_kernel<<<dim3(NBIN), dim3(256), 0, stream>>>(
            feats, weight, gbin, binned, out);

        spill_kernel<<<dim3(64), dim3(256), 0, stream>>>(
            feats, weight, spill_cnt, spill, out);
    } else {
        hipMemsetAsync(d_out, 0, (size_t)out_size * sizeof(float), stream);
        spconvt_fallback<<<dim3((MPAIR + 255) / 256, KOFF), dim3(256), 0, stream>>>(
            feats, weight, in_map, out_map, out);
    }
}

// Round 6
// 436.846 us; speedup vs baseline: 1.5537x; 1.5537x over previous
//
#include <hip/hip_runtime.h>

#define KOFF 27
#define MPAIR 100000
#define NPAIR (KOFF * MPAIR)        // 2,700,000
#define NOUT 400000
#define CIN 32
#define COUT 32

#define ROWS_PER_BIN 256
#define NBIN ((NOUT + ROWS_PER_BIN - 1) / ROWS_PER_BIN)   // 1563
#define CAPB 3072                   // per-bin capacity (avg 1728, +32 sigma)
#define BPB 8192                    // pairs per bin_kernel block
#define SPILL_CAP 65536

// ---------- workspace layout (bytes) ----------
// gbin      @ 0          : NBIN*4 -> pad 8192
// spill_cnt @ 8192       : 256
// spill     @ 8448       : SPILL_CAP*8 = 524,288        -> end 532,736
// binned    @ 532,736    : NBIN*CAPB*4 = 19,206,144     -> end 19,738,880
// per_off   @ 19,738,880 : 2.7M*32*2  = 172,800,000     -> end 192,538,880
// (proven available: >= 225,633,280)
#define O_SPCNT   ((size_t)8192)
#define O_SPILL   ((size_t)8448)
#define O_BINNED  ((size_t)532736)
#define O_PEROFF  ((size_t)19738880)
#define WS_NEED   ((size_t)192538880)

__device__ __forceinline__ unsigned int bf16pair(float a, float b) {
    unsigned int ua = __float_as_uint(a), ub = __float_as_uint(b);
    ua = (ua + 0x7fffu + ((ua >> 16) & 1u)) >> 16;   // RNE
    ub = (ub + 0x7fffu + ((ub >> 16) & 1u)) >> 16;
    return ua | (ub << 16);
}

// ---------- Phase 1: multisplit pair ids by output-row bin (no payload) ----------
__global__ __launch_bounds__(256) void bin_kernel(
    const int* __restrict__ out_map,
    int* __restrict__ gbin, int* __restrict__ binned,
    int* __restrict__ spill_cnt, int2* __restrict__ spill)
{
    __shared__ int lhist[NBIN];              // count, then running cursor
    const int t = threadIdx.x;
    const int base = blockIdx.x * BPB;

    for (int c = t; c < NBIN; c += 256) lhist[c] = 0;
    __syncthreads();

    for (int i = t; i < BPB; i += 256) {
        int p = base + i;
        if (p < NPAIR) atomicAdd(&lhist[out_map[p] >> 8], 1);
    }
    __syncthreads();

    for (int c = t; c < NBIN; c += 256) {
        int cnt = lhist[c];
        lhist[c] = (cnt > 0) ? atomicAdd(&gbin[c], cnt) : 0;  // chunk base
    }
    __syncthreads();

    // scatter packed (rowlocal<<22 | pair_id); chunk-local -> good sectors
    for (int i = t; i < BPB; i += 256) {
        int p = base + i;
        if (p >= NPAIR) continue;
        int row = out_map[p];
        int bin = row >> 8;
        int val = ((row & 255) << 22) | p;
        int pos = atomicAdd(&lhist[bin], 1);
        if (pos < CAPB) {
            binned[(size_t)bin * CAPB + pos] = val;
        } else {
            int o = atomicAdd(spill_cnt, 1);
            if (o < SPILL_CAP) spill[o] = make_int2(row, p);
        }
    }
}

// ---------- Phase 2: per-pair matvec, contiguous bf16 stores (no atomics) ----------
__global__ __launch_bounds__(256) void mv_kernel(
    const float* __restrict__ feats, const float* __restrict__ weight,
    const int* __restrict__ in_map, unsigned short* __restrict__ per_off)
{
    const int k = blockIdx.y;                 // wave-uniform -> SGPR weights
    const int m = blockIdx.x * 256 + threadIdx.x;
    if (m >= MPAIR) return;
    const int p = k * MPAIR + m;
    const int in_row = in_map[p];

    const float4* frow = reinterpret_cast<const float4*>(feats + (size_t)in_row * CIN);
    float4 f4[8];
#pragma unroll
    for (int i = 0; i < 8; ++i) f4[i] = frow[i];
    const float* f = reinterpret_cast<const float*>(f4);

    float acc[COUT];
#pragma unroll
    for (int i = 0; i < COUT; ++i) acc[i] = 0.f;

    const float* wk = weight + (size_t)k * (CIN * COUT);
#pragma unroll
    for (int ci = 0; ci < CIN; ++ci) {
        const float fv = f[ci];
#pragma unroll
        for (int co = 0; co < COUT; ++co)
            acc[co] = fmaf(fv, wk[ci * COUT + co], acc[co]);
    }

    uint4 u[4];
#pragma unroll
    for (int j = 0; j < 4; ++j) {
        u[j].x = bf16pair(acc[8 * j + 0], acc[8 * j + 1]);
        u[j].y = bf16pair(acc[8 * j + 2], acc[8 * j + 3]);
        u[j].z = bf16pair(acc[8 * j + 4], acc[8 * j + 5]);
        u[j].w = bf16pair(acc[8 * j + 6], acc[8 * j + 7]);
    }
    uint4* dst = reinterpret_cast<uint4*>(per_off + (size_t)p * COUT);
#pragma unroll
    for (int j = 0; j < 4; ++j) dst[j] = u[j];   // 64B contiguous store
}

// ---------- Phase 3: per-bin counting-sort + register-accumulate gather ----------
__global__ __launch_bounds__(256) void gather_bin_kernel(
    const unsigned short* __restrict__ per_off,
    const int* __restrict__ gbin, const int* __restrict__ binned,
    float* __restrict__ out)
{
    __shared__ int raw[CAPB];                // 12 KB
    __shared__ int sorted[CAPB];             // 12 KB
    __shared__ int cnt[ROWS_PER_BIN];        // 1 KB
    __shared__ int scan[ROWS_PER_BIN];       // 1 KB (inclusive prefix)
    __shared__ int cur[ROWS_PER_BIN];        // 1 KB

    const int bin = blockIdx.x;
    const int t = threadIdx.x;
    const int n = min(gbin[bin], CAPB);
    const int* mybin = binned + (size_t)bin * CAPB;

    cnt[t] = 0;
    __syncthreads();

    // stage + count
    for (int i = t; i < n; i += 256) {
        int v = mybin[i];                    // coalesced
        raw[i] = v;
        atomicAdd(&cnt[(v >> 22) & 255], 1);
    }
    __syncthreads();

    // Hillis-Steele inclusive scan over 256 counters
    scan[t] = cnt[t];
    __syncthreads();
#pragma unroll
    for (int off = 1; off < 256; off <<= 1) {
        int v = (t >= off) ? scan[t - off] : 0;
        __syncthreads();
        scan[t] += v;
        __syncthreads();
    }
    cur[t] = scan[t] - cnt[t];               // exclusive start
    __syncthreads();

    // scatter into row-sorted order (store pair id only)
    for (int i = t; i < n; i += 256) {
        int v = raw[i];
        int pos = atomicAdd(&cur[(v >> 22) & 255], 1);
        sorted[pos] = v & 0x3FFFFF;
    }
    __syncthreads();

    // 32-lane group per row: random 64B payload reads, register accumulate
    const int group = t >> 5;                // 8 groups
    const int lane = t & 31;
    for (int r = group; r < ROWS_PER_BIN; r += 8) {
        int grow = (bin << 8) + r;
        if (grow >= NOUT) break;
        int s1 = scan[r];
        int s0 = s1 - cnt[r];
        float acc = 0.f;
        for (int i = s0; i < s1; ++i) {
            int p = sorted[i];               // LDS broadcast
            unsigned short v = per_off[(size_t)p * COUT + lane];  // 64B/group
            acc += __uint_as_float(((unsigned int)v) << 16);
        }
        out[(size_t)grow * COUT + lane] = acc;   // coalesced 128B/group
    }
}

// ---------- Phase 4: statistically-rare bin overflow, recompute + atomics ----------
__global__ __launch_bounds__(256) void spill_kernel(
    const float* __restrict__ feats, const float* __restrict__ weight,
    const int* __restrict__ in_map,
    const int* __restrict__ spill_cnt, const int2* __restrict__ spill,
    float* __restrict__ out)
{
    int n = min(*spill_cnt, SPILL_CAP);
    for (int i = blockIdx.x * blockDim.x + threadIdx.x; i < n * 32;
         i += gridDim.x * blockDim.x) {
        int idx = i >> 5, co = i & 31;
        int2 s = spill[idx];
        int row = s.x;
        int p   = s.y;
        int k   = p / MPAIR;
        int irow = in_map[p];
        const float* f  = feats + (size_t)irow * CIN;
        const float* wk = weight + (size_t)k * (CIN * COUT);
        float acc = 0.f;
#pragma unroll
        for (int ci = 0; ci < CIN; ++ci)
            acc = fmaf(f[ci], wk[ci * COUT + co], acc);
        atomicAdd(&out[(size_t)row * COUT + co], acc);
    }
}

// ---------- last-resort fallback (tiny ws): R1 atomic scatter ----------
__global__ __launch_bounds__(256) void spconvt_fallback(
    const float* __restrict__ feats, const float* __restrict__ weight,
    const int* __restrict__ in_map, const int* __restrict__ out_map,
    float* __restrict__ out)
{
    const int k = blockIdx.y;
    const int m = blockIdx.x * blockDim.x + threadIdx.x;
    const bool active = (m < MPAIR);
    const int mm = active ? m : (MPAIR - 1);
    const int pair = k * MPAIR + mm;
    const int in_row = in_map[pair];
    const int out_row = out_map[pair];
    const float4* frow = reinterpret_cast<const float4*>(feats + (size_t)in_row * CIN);
    float4 f4[8];
#pragma unroll
    for (int i = 0; i < 8; ++i) f4[i] = frow[i];
    const float* f = reinterpret_cast<const float*>(f4);
    float acc[COUT];
#pragma unroll
    for (int i = 0; i < COUT; ++i) acc[i] = 0.f;
    const float* wk = weight + (size_t)k * (CIN * COUT);
#pragma unroll
    for (int ci = 0; ci < CIN; ++ci) {
        const float fv = f[ci];
#pragma unroll
        for (int co = 0; co < COUT; ++co)
            acc[co] = fmaf(fv, wk[ci * COUT + co], acc[co]);
    }
    if (active) {
        float* orow = out + (size_t)out_row * COUT;
#pragma unroll
        for (int co = 0; co < COUT; ++co) atomicAdd(orow + co, acc[co]);
    }
}

extern "C" void kernel_launch(void* const* d_in, const int* in_sizes, int n_in,
                              void* d_out, int out_size, void* d_ws, size_t ws_size,
                              hipStream_t stream) {
    const float* feats  = (const float*)d_in[0];
    const float* weight = (const float*)d_in[1];
    const int* in_map   = (const int*)d_in[2];
    const int* out_map  = (const int*)d_in[3];
    float* out          = (float*)d_out;
    char* ws            = (char*)d_ws;

    if (ws_size >= WS_NEED) {
        int* gbin               = (int*)(ws);
        int* spill_cnt          = (int*)(ws + O_SPCNT);
        int2* spill             = (int2*)(ws + O_SPILL);
        int* binned             = (int*)(ws + O_BINNED);
        unsigned short* per_off = (unsigned short*)(ws + O_PEROFF);

        hipMemsetAsync(ws, 0, O_SPILL, stream);   // gbin + spill_cnt only

        bin_kernel<<<dim3((NPAIR + BPB - 1) / BPB), dim3(256), 0, stream>>>(
            out_map, gbin, binned, spill_cnt, spill);

        mv_kernel<<<dim3((MPAIR + 255) / 256, KOFF), dim3(256), 0, stream>>>(
            feats, weight, in_map, per_off);

        gather_bin_kernel<<<dim3(NBIN), dim3(256), 0, stream>>>(
            per_off, gbin, binned, out);

        spill_kernel<<<dim3(64), dim3(256), 0, stream>>>(
            feats, weight, in_map, spill_cnt, spill, out);
    } else {
        hipMemsetAsync(d_out, 0, (size_t)out_size * sizeof(float), stream);
        spconvt_fallback<<<dim3((MPAIR + 255) / 256, KOFF), dim3(256), 0, stream>>>(
            feats, weight, in_map, out_map, out);
    }
}